// Round 1
// baseline (1489.459 us; speedup 1.0000x reference)
//
#include <hip/hip_runtime.h>
#include <hip/hip_bf16.h>
#include <cstdint>

#define N_ROWS 131072   // 32*4096
#define DDIM   128
#define KCODE  512
#define TM     64       // rows per block (K1)
#define TN     32       // codes per LDS tile (K1)
#define NTILES (KCODE/TN)
#define LDX    132      // padded LDS row stride (floats), 16B aligned, breaks bank conflicts
#define SC     4096     // rows scanned per chunk in K2

// ---------------- threefry2x32 (JAX-compatible) ----------------
__device__ __forceinline__ uint32_t rotl32(uint32_t x, uint32_t n) {
    return (x << n) | (x >> (32 - n));
}
__device__ __forceinline__ void threefry2x32(uint32_t k0, uint32_t k1,
                                             uint32_t x0, uint32_t x1,
                                             uint32_t& o0, uint32_t& o1) {
    uint32_t ks[3] = {k0, k1, k0 ^ k1 ^ 0x1BD11BDAu};
    x0 += ks[0]; x1 += ks[1];
    const uint32_t rA[4] = {13, 15, 26, 6};
    const uint32_t rB[4] = {17, 29, 16, 24};
#pragma unroll
    for (int i = 0; i < 5; ++i) {
        const uint32_t* r = (i & 1) ? rB : rA;
#pragma unroll
        for (int j = 0; j < 4; ++j) { x0 += x1; x1 = rotl32(x1, r[j]); x1 ^= x0; }
        x0 += ks[(i + 1) % 3];
        x1 += ks[(i + 2) % 3] + (uint32_t)(i + 1);
    }
    o0 = x0; o1 = x1;
}
// JAX randint bit-mixing (uint32 wraparound arithmetic, matches lax ops exactly)
__device__ __forceinline__ uint32_t jax_randint_from_bits(uint32_t bits, uint32_t span) {
    uint32_t mult = 65536u % span;
    mult = (uint32_t)(mult * mult) % span;
    uint32_t hi = bits >> 16, lo = bits & 0xFFFFu;
    uint32_t off = (hi % span) * mult + (lo % span);
    return off % span;
}

// ---------------- K0: ||e||^2 per code + zero scalars ----------------
__global__ void k0_esq(const float* __restrict__ emb, float* __restrict__ esq,
                       float* __restrict__ ws_sc) {
    int k = blockIdx.x, t = threadIdx.x; // 512 blocks x 64 threads
    float a = emb[k * DDIM + t];
    float b = emb[k * DDIM + 64 + t];
    float v = a * a + b * b;
#pragma unroll
    for (int o = 32; o > 0; o >>= 1) v += __shfl_down(v, o);
    if (t == 0) esq[k] = v;
    if (k == 0 && t < 2) ws_sc[t] = 0.0f;  // [0]=loss sum, [1]=n sum
}

// ---------------- K1: distances + argmin + quantize + loss ----------------
__global__ __launch_bounds__(256) void k1_assign(
    const float* __restrict__ x, const float* __restrict__ emb,
    const float* __restrict__ esq,
    float* __restrict__ out_q, float* __restrict__ out_idx_f,
    int* __restrict__ ws_idx, float* __restrict__ ws_sc) {

    __shared__ float Xs[TM * LDX];
    __shared__ float Es[TN * LDX];
    __shared__ float rmin[TM * 16];
    __shared__ int   ridx[TM * 16];
    __shared__ float xsq_s[TM];
    __shared__ int   idxf[TM];
    __shared__ float lred[4];

    const int t = threadIdx.x;
    const int blk = blockIdx.x;
    const int rowbase = blk * TM;

    // load X tile (contiguous 64*128 floats)
    {
        const float4* src = (const float4*)(x + (size_t)rowbase * DDIM);
        for (int i = t; i < TM * DDIM / 4; i += 256) {
            float4 v = src[i];
            int fi = i * 4;
            *(float4*)&Xs[(fi >> 7) * LDX + (fi & 127)] = v;
        }
    }
    __syncthreads();
    if (t < TM) { // per-row ||x||^2
        float s = 0.0f;
#pragma unroll 8
        for (int d = 0; d < DDIM; ++d) { float v = Xs[t * LDX + d]; s = fmaf(v, v, s); }
        xsq_s[t] = s;
    }

    const int ti = t & 15, tj = t >> 4;
    float bmin[4];
    int   bidx[4];
#pragma unroll
    for (int m = 0; m < 4; ++m) { bmin[m] = 3.4e38f; bidx[m] = 0; }

    for (int ct = 0; ct < NTILES; ++ct) {
        __syncthreads(); // protect Es reuse (also publishes xsq_s on first iter)
        {
            const float4* esrc = (const float4*)(emb + (size_t)ct * TN * DDIM);
            for (int i = t; i < TN * DDIM / 4; i += 256) {
                float4 v = esrc[i];
                int fi = i * 4;
                *(float4*)&Es[(fi >> 7) * LDX + (fi & 127)] = v;
            }
        }
        __syncthreads();

        float acc[4][2];
#pragma unroll
        for (int m = 0; m < 4; ++m)
#pragma unroll
            for (int c = 0; c < 2; ++c) acc[m][c] = 0.0f;

#pragma unroll 4
        for (int d = 0; d < DDIM; d += 4) {
            float4 xv[4], ev[2];
#pragma unroll
            for (int m = 0; m < 4; ++m) xv[m] = *(const float4*)&Xs[(ti + 16 * m) * LDX + d];
#pragma unroll
            for (int c = 0; c < 2; ++c) ev[c] = *(const float4*)&Es[(tj + 16 * c) * LDX + d];
#pragma unroll
            for (int m = 0; m < 4; ++m)
#pragma unroll
                for (int c = 0; c < 2; ++c) {
                    float a = acc[m][c];
                    a = fmaf(xv[m].x, ev[c].x, a);
                    a = fmaf(xv[m].y, ev[c].y, a);
                    a = fmaf(xv[m].z, ev[c].z, a);
                    a = fmaf(xv[m].w, ev[c].w, a);
                    acc[m][c] = a;
                }
        }

#pragma unroll
        for (int c = 0; c < 2; ++c) {
            int code = ct * TN + tj + 16 * c;
            float eq = esq[code];
#pragma unroll
            for (int m = 0; m < 4; ++m) {
                float t1 = xsq_s[ti + 16 * m] + eq;       // mimic ref: (xsq+esq) - 2*dot
                float dist = t1 - 2.0f * acc[m][c];
                if (dist < bmin[m]) { bmin[m] = dist; bidx[m] = code; }
            }
        }
    }

    __syncthreads();
#pragma unroll
    for (int m = 0; m < 4; ++m) {
        rmin[(ti + 16 * m) * 16 + tj] = bmin[m];
        ridx[(ti + 16 * m) * 16 + tj] = bidx[m];
    }
    __syncthreads();
    if (t < TM) {
        float mv = rmin[t * 16]; int mi = ridx[t * 16];
#pragma unroll
        for (int j = 1; j < 16; ++j) {
            float v = rmin[t * 16 + j]; int ii = ridx[t * 16 + j];
            if (v < mv || (v == mv && ii < mi)) { mv = v; mi = ii; }
        }
        idxf[t] = mi;
        int gr = rowbase + t;
        ws_idx[gr] = mi;
        out_idx_f[gr] = (float)mi;
    }
    __syncthreads();

    // epilogue: quantize + straight-through + loss partial
    float lacc = 0.0f;
    for (int j = t; j < TM * DDIM; j += 256) {
        int r = j >> 7, d = j & 127;
        int ci = idxf[r];
        float q = emb[ci * DDIM + d];
        float xv = Xs[r * LDX + d];
        float df = q - xv;
        out_q[(size_t)(rowbase + r) * DDIM + d] = xv + df;
        lacc = fmaf(df, df, lacc);
    }
#pragma unroll
    for (int o = 32; o > 0; o >>= 1) lacc += __shfl_down(lacc, o);
    if ((t & 63) == 0) lred[t >> 6] = lacc;
    __syncthreads();
    if (t == 0) atomicAdd(&ws_sc[0], lred[0] + lred[1] + lred[2] + lred[3]);
}

// ---------------- K2: per-cluster counts + dw (scan + gather) ----------------
__global__ __launch_bounds__(256) void k2_seg(
    const int* __restrict__ ws_idx, const float* __restrict__ x,
    const float* __restrict__ ema_cs,
    float* __restrict__ ws_dw, float* __restrict__ ws_csr,
    float* __restrict__ ws_sc) {

    const int k = blockIdx.x;  // cluster id, 512 blocks
    const int t = threadIdx.x; // 256
    __shared__ int   lst[SC];
    __shared__ int   cnt_s;
    __shared__ int   total_s;
    __shared__ float hsum[128];
    if (t == 0) { cnt_s = 0; total_s = 0; }
    __syncthreads();

    const int d = t & 127, h = t >> 7;
    float acc = 0.0f;

    for (int base = 0; base < N_ROWS; base += SC) {
#pragma unroll
        for (int u = 0; u < SC / 256; ++u) {
            int row = base + u * 256 + t;
            if (ws_idx[row] == k) { int p = atomicAdd(&cnt_s, 1); lst[p] = row; }
        }
        __syncthreads();
        int c = cnt_s;
        for (int i = h; i < c; i += 2)
            acc += x[(size_t)lst[i] * DDIM + d];
        __syncthreads();
        if (t == 0) { total_s += c; cnt_s = 0; }
        __syncthreads();
    }

    if (h == 1) hsum[d] = acc;
    __syncthreads();
    if (h == 0) ws_dw[k * DDIM + d] = acc + hsum[d];
    if (t == 0) {
        float raw = 0.99f * ema_cs[k] + 0.01f * (float)total_s;
        ws_csr[k] = raw;
        atomicAdd(&ws_sc[1], raw);
    }
}

// ---------------- K3: normalize cluster sizes, loss, threefry rand ----------------
__global__ void k3_cs(const float* __restrict__ ws_csr, const float* __restrict__ ws_sc,
                      float* __restrict__ out_loss, float* __restrict__ out_cs,
                      float* __restrict__ ws_csn, int* __restrict__ ws_rand) {
    int t = threadIdx.x; // 512
    float n = ws_sc[1];
    if (t < KCODE) {
        float raw = ws_csr[t];
        float csn = (raw + 1e-5f) / (n + 512.0f * 1e-5f) * n;
        ws_csn[t] = csn;
        out_cs[t] = (csn < 1.0f) ? 1.0f : csn;
    }
    if (t < 256) {
        uint32_t o0, o1;
        threefry2x32(0u, 42u, (uint32_t)t, (uint32_t)(t + 256), o0, o1);
        ws_rand[t]       = (int)jax_randint_from_bits(o0, (uint32_t)N_ROWS);
        ws_rand[t + 256] = (int)jax_randint_from_bits(o1, (uint32_t)N_ROWS);
    }
    if (t == 0) out_loss[0] = 0.25f * ws_sc[0] / (float)(N_ROWS * DDIM);
}

// ---------------- K4: EMA update + dead-code reinit ----------------
__global__ void k4_update(const float* __restrict__ ws_dw, const float* __restrict__ ema_w,
                          const float* __restrict__ ws_csn, const int* __restrict__ ws_rand,
                          const float* __restrict__ x,
                          float* __restrict__ out_ne, float* __restrict__ out_nw) {
    int k = blockIdx.x, d = threadIdx.x; // 512 x 128
    float nw = 0.99f * ema_w[k * DDIM + d] + 0.01f * ws_dw[k * DDIM + d];
    float cs = ws_csn[k];
    float ne = nw / cs;
    if (cs < 1.0f) {
        float r = x[(size_t)ws_rand[k] * DDIM + d];
        ne = r; nw = r;
    }
    out_ne[k * DDIM + d] = ne;
    out_nw[k * DDIM + d] = nw;
}

extern "C" void kernel_launch(void* const* d_in, const int* in_sizes, int n_in,
                              void* d_out, int out_size, void* d_ws, size_t ws_size,
                              hipStream_t stream) {
    const float* x      = (const float*)d_in[0]; // [N, 128]
    const float* emb    = (const float*)d_in[1]; // [512, 128]
    const float* ema_cs = (const float*)d_in[2]; // [512]
    const float* ema_w  = (const float*)d_in[3]; // [512, 128]

    float* out = (float*)d_out;
    float* out_q    = out;                       // 16777216
    float* out_loss = out + 16777216;            // 1
    float* out_idx  = out + 16777217;            // 131072
    float* out_ne   = out + 16908289;            // 65536
    float* out_cs   = out + 16973825;            // 512
    float* out_nw   = out + 16974337;            // 65536

    char* w = (char*)d_ws;
    int*   ws_idx  = (int*)  (w);                 // 524288 B
    float* ws_dw   = (float*)(w + 524288);        // 262144 B
    float* ws_csr  = (float*)(w + 786432);        // 2048 B
    float* ws_csn  = (float*)(w + 788480);        // 2048 B
    int*   ws_rand = (int*)  (w + 790528);        // 2048 B
    float* ws_esq  = (float*)(w + 792576);        // 2048 B
    float* ws_sc   = (float*)(w + 794624);        // 8 B: [0]=loss, [1]=n

    k0_esq<<<KCODE, 64, 0, stream>>>(emb, ws_esq, ws_sc);
    k1_assign<<<N_ROWS / TM, 256, 0, stream>>>(x, emb, ws_esq, out_q, out_idx, ws_idx, ws_sc);
    k2_seg<<<KCODE, 256, 0, stream>>>(ws_idx, x, ema_cs, ws_dw, ws_csr, ws_sc);
    k3_cs<<<1, 512, 0, stream>>>(ws_csr, ws_sc, out_loss, out_cs, ws_csn, ws_rand);
    k4_update<<<KCODE, DDIM, 0, stream>>>(ws_dw, ema_w, ws_csn, ws_rand, x, out_ne, out_nw);
}

// Round 2
// 512.017 us; speedup vs baseline: 2.9090x; 2.9090x over previous
//
#include <hip/hip_runtime.h>
#include <hip/hip_bf16.h>
#include <cstdint>

#define N_ROWS 131072   // 32*4096
#define DDIM   128
#define KCODE  512
#define TM     64       // rows per block (K1)
#define TN     32       // codes per LDS tile (K1)
#define NTILES (KCODE/TN)
#define LDX    132      // padded LDS row stride (floats), 16B aligned, breaks bank conflicts

// ---------------- threefry2x32 (JAX-compatible) ----------------
__device__ __forceinline__ uint32_t rotl32(uint32_t x, uint32_t n) {
    return (x << n) | (x >> (32 - n));
}
__device__ __forceinline__ void threefry2x32(uint32_t k0, uint32_t k1,
                                             uint32_t x0, uint32_t x1,
                                             uint32_t& o0, uint32_t& o1) {
    uint32_t ks[3] = {k0, k1, k0 ^ k1 ^ 0x1BD11BDAu};
    x0 += ks[0]; x1 += ks[1];
    const uint32_t rA[4] = {13, 15, 26, 6};
    const uint32_t rB[4] = {17, 29, 16, 24};
#pragma unroll
    for (int i = 0; i < 5; ++i) {
        const uint32_t* r = (i & 1) ? rB : rA;
#pragma unroll
        for (int j = 0; j < 4; ++j) { x0 += x1; x1 = rotl32(x1, r[j]); x1 ^= x0; }
        x0 += ks[(i + 1) % 3];
        x1 += ks[(i + 2) % 3] + (uint32_t)(i + 1);
    }
    o0 = x0; o1 = x1;
}
__device__ __forceinline__ uint32_t jax_randint_from_bits(uint32_t bits, uint32_t span) {
    uint32_t mult = 65536u % span;
    mult = (uint32_t)(mult * mult) % span;
    uint32_t hi = bits >> 16, lo = bits & 0xFFFFu;
    uint32_t off = (hi % span) * mult + (lo % span);
    return off % span;
}

// ---------------- K0: ||e||^2 per code ----------------
__global__ void k0_esq(const float* __restrict__ emb, float* __restrict__ esq) {
    int k = blockIdx.x, t = threadIdx.x; // 512 blocks x 64 threads
    float a = emb[k * DDIM + t];
    float b = emb[k * DDIM + 64 + t];
    float v = a * a + b * b;
#pragma unroll
    for (int o = 32; o > 0; o >>= 1) v += __shfl_down(v, o);
    if (t == 0) esq[k] = v;
}

// ---------------- K1: distances + argmin + quantize + loss + dw/count scatter ----------------
__global__ __launch_bounds__(256) void k1_assign(
    const float* __restrict__ x, const float* __restrict__ emb,
    const float* __restrict__ esq,
    float* __restrict__ out_q, float* __restrict__ out_idx_f,
    float* __restrict__ ws_dw, int* __restrict__ ws_cnt,
    float* __restrict__ ws_sc) {

    __shared__ float Xs[TM * LDX];
    __shared__ float Es[TN * LDX];
    __shared__ float rmin[TM * 16];
    __shared__ int   ridx[TM * 16];
    __shared__ float xsq_s[TM];
    __shared__ int   idxf[TM];
    __shared__ float lred[4];

    const int t = threadIdx.x;
    const int blk = blockIdx.x;
    const int rowbase = blk * TM;

    // load X tile (contiguous 64*128 floats)
    {
        const float4* src = (const float4*)(x + (size_t)rowbase * DDIM);
        for (int i = t; i < TM * DDIM / 4; i += 256) {
            float4 v = src[i];
            int fi = i * 4;
            *(float4*)&Xs[(fi >> 7) * LDX + (fi & 127)] = v;
        }
    }
    __syncthreads();
    if (t < TM) { // per-row ||x||^2
        float s = 0.0f;
#pragma unroll 8
        for (int d = 0; d < DDIM; ++d) { float v = Xs[t * LDX + d]; s = fmaf(v, v, s); }
        xsq_s[t] = s;
    }

    const int ti = t & 15, tj = t >> 4;
    float bmin[4];
    int   bidx[4];
#pragma unroll
    for (int m = 0; m < 4; ++m) { bmin[m] = 3.4e38f; bidx[m] = 0; }

    for (int ct = 0; ct < NTILES; ++ct) {
        __syncthreads(); // protect Es reuse (also publishes xsq_s on first iter)
        {
            const float4* esrc = (const float4*)(emb + (size_t)ct * TN * DDIM);
            for (int i = t; i < TN * DDIM / 4; i += 256) {
                float4 v = esrc[i];
                int fi = i * 4;
                *(float4*)&Es[(fi >> 7) * LDX + (fi & 127)] = v;
            }
        }
        __syncthreads();

        float acc[4][2];
#pragma unroll
        for (int m = 0; m < 4; ++m)
#pragma unroll
            for (int c = 0; c < 2; ++c) acc[m][c] = 0.0f;

#pragma unroll 4
        for (int d = 0; d < DDIM; d += 4) {
            float4 xv[4], ev[2];
#pragma unroll
            for (int m = 0; m < 4; ++m) xv[m] = *(const float4*)&Xs[(ti + 16 * m) * LDX + d];
#pragma unroll
            for (int c = 0; c < 2; ++c) ev[c] = *(const float4*)&Es[(tj + 16 * c) * LDX + d];
#pragma unroll
            for (int m = 0; m < 4; ++m)
#pragma unroll
                for (int c = 0; c < 2; ++c) {
                    float a = acc[m][c];
                    a = fmaf(xv[m].x, ev[c].x, a);
                    a = fmaf(xv[m].y, ev[c].y, a);
                    a = fmaf(xv[m].z, ev[c].z, a);
                    a = fmaf(xv[m].w, ev[c].w, a);
                    acc[m][c] = a;
                }
        }

#pragma unroll
        for (int c = 0; c < 2; ++c) {
            int code = ct * TN + tj + 16 * c;
            float eq = esq[code];
#pragma unroll
            for (int m = 0; m < 4; ++m) {
                float t1 = xsq_s[ti + 16 * m] + eq;       // mimic ref: (xsq+esq) - 2*dot
                float dist = t1 - 2.0f * acc[m][c];
                if (dist < bmin[m]) { bmin[m] = dist; bidx[m] = code; }
            }
        }
    }

    __syncthreads();
#pragma unroll
    for (int m = 0; m < 4; ++m) {
        rmin[(ti + 16 * m) * 16 + tj] = bmin[m];
        ridx[(ti + 16 * m) * 16 + tj] = bidx[m];
    }
    __syncthreads();
    if (t < TM) {
        float mv = rmin[t * 16]; int mi = ridx[t * 16];
#pragma unroll
        for (int j = 1; j < 16; ++j) {
            float v = rmin[t * 16 + j]; int ii = ridx[t * 16 + j];
            if (v < mv || (v == mv && ii < mi)) { mv = v; mi = ii; }
        }
        idxf[t] = mi;
        int gr = rowbase + t;
        out_idx_f[gr] = (float)mi;
        atomicAdd(&ws_cnt[mi], 1);          // cluster count scatter
    }
    __syncthreads();

    // epilogue: quantize + straight-through + loss partial + dw scatter
    float lacc = 0.0f;
    for (int j = t; j < TM * DDIM; j += 256) {
        int r = j >> 7, d = j & 127;
        int ci = idxf[r];
        float q = emb[ci * DDIM + d];
        float xv = Xs[r * LDX + d];
        float df = q - xv;
        out_q[(size_t)(rowbase + r) * DDIM + d] = xv + df;
        atomicAdd(&ws_dw[ci * DDIM + d], xv);   // dw segment-sum scatter
        lacc = fmaf(df, df, lacc);
    }
#pragma unroll
    for (int o = 32; o > 0; o >>= 1) lacc += __shfl_down(lacc, o);
    if ((t & 63) == 0) lred[t >> 6] = lacc;
    __syncthreads();
    if (t == 0) atomicAdd(&ws_sc[0], lred[0] + lred[1] + lred[2] + lred[3]);
}

// ---------------- K3: cluster-size EMA+normalize, loss, threefry rand ----------------
__global__ __launch_bounds__(512) void k3_cs(
    const int* __restrict__ ws_cnt, const float* __restrict__ ema_cs,
    const float* __restrict__ ws_sc,
    float* __restrict__ out_loss, float* __restrict__ out_cs,
    float* __restrict__ ws_csn, int* __restrict__ ws_rand) {
    __shared__ float red[8];
    int t = threadIdx.x; // 512
    float raw = 0.99f * ema_cs[t] + 0.01f * (float)ws_cnt[t];
    // block-reduce sum of raw -> n
    float s = raw;
#pragma unroll
    for (int o = 32; o > 0; o >>= 1) s += __shfl_down(s, o);
    if ((t & 63) == 0) red[t >> 6] = s;
    __syncthreads();
    float n;
    {
        float r0 = (t < 8) ? red[t] : 0.0f;
        // broadcast full sum via lane reads (all threads recompute)
        n = red[0] + red[1] + red[2] + red[3] + red[4] + red[5] + red[6] + red[7];
        (void)r0;
    }
    float csn = (raw + 1e-5f) / (n + 512.0f * 1e-5f) * n;
    ws_csn[t] = csn;
    out_cs[t] = (csn < 1.0f) ? 1.0f : csn;
    if (t < 256) {
        uint32_t o0, o1;
        threefry2x32(0u, 42u, (uint32_t)t, (uint32_t)(t + 256), o0, o1);
        ws_rand[t]       = (int)jax_randint_from_bits(o0, (uint32_t)N_ROWS);
        ws_rand[t + 256] = (int)jax_randint_from_bits(o1, (uint32_t)N_ROWS);
    }
    if (t == 0) out_loss[0] = 0.25f * ws_sc[0] / (float)(N_ROWS * DDIM);
}

// ---------------- K4: EMA update + dead-code reinit ----------------
__global__ void k4_update(const float* __restrict__ ws_dw, const float* __restrict__ ema_w,
                          const float* __restrict__ ws_csn, const int* __restrict__ ws_rand,
                          const float* __restrict__ x,
                          float* __restrict__ out_ne, float* __restrict__ out_nw) {
    int k = blockIdx.x, d = threadIdx.x; // 512 x 128
    float nw = 0.99f * ema_w[k * DDIM + d] + 0.01f * ws_dw[k * DDIM + d];
    float cs = ws_csn[k];
    float ne = nw / cs;
    if (cs < 1.0f) {
        float r = x[(size_t)ws_rand[k] * DDIM + d];
        ne = r; nw = r;
    }
    out_ne[k * DDIM + d] = ne;
    out_nw[k * DDIM + d] = nw;
}

extern "C" void kernel_launch(void* const* d_in, const int* in_sizes, int n_in,
                              void* d_out, int out_size, void* d_ws, size_t ws_size,
                              hipStream_t stream) {
    const float* x      = (const float*)d_in[0]; // [N, 128]
    const float* emb    = (const float*)d_in[1]; // [512, 128]
    const float* ema_cs = (const float*)d_in[2]; // [512]
    const float* ema_w  = (const float*)d_in[3]; // [512, 128]

    float* out = (float*)d_out;
    float* out_q    = out;                       // 16777216
    float* out_loss = out + 16777216;            // 1
    float* out_idx  = out + 16777217;            // 131072
    float* out_ne   = out + 16908289;            // 65536
    float* out_cs   = out + 16973825;            // 512
    float* out_nw   = out + 16974337;            // 65536

    char* w = (char*)d_ws;
    float* ws_dw   = (float*)(w);                 // 262144 B  [zeroed]
    int*   ws_cnt  = (int*)  (w + 262144);        // 2048 B    [zeroed]
    float* ws_sc   = (float*)(w + 264192);        // 64 B      [zeroed; [0]=loss sum]
    float* ws_csn  = (float*)(w + 264256);        // 2048 B
    int*   ws_rand = (int*)  (w + 266304);        // 2048 B
    float* ws_esq  = (float*)(w + 268352);        // 2048 B

    hipMemsetAsync(d_ws, 0, 264256, stream);      // dw + cnt + sc

    k0_esq<<<KCODE, 64, 0, stream>>>(emb, ws_esq);
    k1_assign<<<N_ROWS / TM, 256, 0, stream>>>(x, emb, ws_esq, out_q, out_idx,
                                               ws_dw, ws_cnt, ws_sc);
    k3_cs<<<1, 512, 0, stream>>>(ws_cnt, ema_cs, ws_sc, out_loss, out_cs, ws_csn, ws_rand);
    k4_update<<<KCODE, DDIM, 0, stream>>>(ws_dw, ema_w, ws_csn, ws_rand, x, out_ne, out_nw);
}